// Round 13
// baseline (202.959 us; speedup 1.0000x reference)
//
#include <hip/hip_runtime.h>
#include <stdint.h>

typedef unsigned short u16;
typedef __attribute__((ext_vector_type(8))) short short8;
typedef __attribute__((ext_vector_type(4))) float f32x4;
typedef __attribute__((ext_vector_type(4))) unsigned int u32x4;

#define NTRACE 4096
#define TLEN   64
#define ISZ    64
#define HSZ    128
#define NBIN   64

#define LOG2E     1.44269504088896f
#define TWOLOG2E  2.88539008177793f

__device__ __forceinline__ float bflo(uint32_t u) {
  union { uint32_t i; float f; } v; v.i = u << 16; return v.f;
}
__device__ __forceinline__ float bfhi(uint32_t u) {
  union { uint32_t i; float f; } v; v.i = u & 0xffff0000u; return v.f;
}
__device__ __forceinline__ u16 f2bf(float f) {
  union { float f; uint32_t i; } v; v.f = f;
  uint32_t r = v.i + 0x7fffu + ((v.i >> 16) & 1u);
  return (u16)(r >> 16);
}
__device__ __forceinline__ float fexp2(float x) {
  float r;
  asm("v_exp_f32 %0, %1" : "=v"(r) : "v"(x));
  return r;
}
// tanh(a)*sigmoid(b) with pre-scaled gates: gB=-log2e*b, gE=2log2e*a
__device__ __forceinline__ float gate2(float gB, float gE) {
  float E = fexp2(gE);
  float B = fexp2(gB);
  return (E - 1.0f) * __builtin_amdgcn_rcpf((E + 1.0f) * (1.0f + B));
}
__device__ __forceinline__ short8 mk8(uint32_t a, uint32_t b, uint32_t c, uint32_t d) {
  union { short8 s; uint32_t u[4]; } z;
  z.u[0] = a; z.u[1] = b; z.u[2] = c; z.u[3] = d; return z.s;
}
// Weight-row permutation (R6-VERIFIED): buffer tile-row rr holds true hidden
// index pi(rr); MFMA C output renames register-only into the next layer's
// B-fragment (linear k): frag ks elem j = h[ks*32+q*8+j].
__device__ __forceinline__ int perm128(int rr) {
  return ((rr >> 4) & 3) * 32 + ((rr >> 2) & 3) * 8 + ((rr >> 6) & 1) * 4 + (rr & 3);
}

// ---------------------------------------------------------------------------
// k_prep (R6-VERIFIED, verbatim): bf16 weights with exp2 scale folding + pi
// row permutation; emb->bf16; bins zero.
// ---------------------------------------------------------------------------
__global__ __launch_bounds__(256) void k_prep(
    const float* __restrict__ emb,
    const float* __restrict__ W1, const float* __restrict__ W2,
    const float* __restrict__ Wp1,
    const float* __restrict__ b_ih1, const float* __restrict__ b_hh1,
    const float* __restrict__ b_ih2, const float* __restrict__ b_hh2,
    u16* __restrict__ embb,
    u16* __restrict__ w1b, u16* __restrict__ w2b, u16* __restrict__ wp1b,
    float* __restrict__ bs1, float* __restrict__ bs2,
    float* __restrict__ bins)
{
  const int i = blockIdx.x * 256 + threadIdx.x;   // 65536 threads
  if (i < 512 * 64) {
    const int row = i >> 6, G = row >> 7, rr = row & 127;
    const float s = (G == 2) ? TWOLOG2E : -LOG2E;
    w1b[i] = f2bf(W1[(G * 128 + perm128(rr)) * ISZ + (i & 63)] * s);
  }
  if (i < 512 * 128) {
    const int row = i >> 7, G = row >> 7, rr = row & 127;
    const float s = (G == 2) ? TWOLOG2E : -LOG2E;
    w2b[i] = f2bf(W2[(G * 128 + perm128(rr)) * HSZ + (i & 127)] * s);
  }
  if (i < 64 * 128) wp1b[i] = f2bf(Wp1[i]);
  if (i < 512) {
    const int G = i >> 7, rr = i & 127;
    const float s = (G == 2) ? TWOLOG2E : -LOG2E;
    const int src = G * 128 + perm128(rr);
    bs1[i] = (b_ih1[src] + b_hh1[src]) * s;
    bs2[i] = (b_ih2[src] + b_hh2[src]) * s;
  }
  if (i < NBIN * HSZ) bins[i] = 0.f;
  for (int j = i; j < 10000 * 64; j += 256 * 256) embb[j] = f2bf(emb[j]);
}

// ---------------------------------------------------------------------------
// trace_body<NG> (R11-VERIFIED, verbatim): one wave, one trace, fully in
// registers (pi rename); w1/w2 from LDS (compact i@0/g@128/o@256 rows,
// XOR-swizzled); single-shot softmax; in-register weighted sum;
// col-butterfly; one-lane-per-h scatter into bin.
// ---------------------------------------------------------------------------
template<int NG>
__device__ __forceinline__ void trace_body(
    const u16* __restrict__ embb,
    const u16* w1s, const float* __restrict__ bs1,
    const u16* w2s, const float* __restrict__ bs2,
    const u16* __restrict__ wp1b,
    const float* __restrict__ bp1v, const float* __restrict__ Wp2,
    const float* __restrict__ bp2v,
    const int* __restrict__ traces,
    float* __restrict__ bin, int t, int len)
{
  const int lane = threadIdx.x & 63;
  const int col  = lane & 15;
  const int q    = lane >> 4;
  const int sw1  = (col & 7) << 3;   // w1 read XOR (u16 units)
  const int sw2  = col << 3;         // w2 read XOR (u16 units)
  const f32x4 z = {0.f, 0.f, 0.f, 0.f};

  // ---- x fragments (bf16 emb, B-operand of lstm1)
  short8 xf[NG][2];
#pragma unroll
  for (int g = 0; g < NG; ++g) {
    const int tok = traces[t * TLEN + g * 16 + col];
    const u16* xr = embb + (size_t)tok * ISZ + q * 8;
    xf[g][0] = *(const short8*)(xr);
    xf[g][1] = *(const short8*)(xr + 32);
  }

  // ---- LSTM layer 1 (K=64); LDS compact rows: i@0, g@128, o@256
  uint32_t pk[NG][8][2];
#pragma unroll
  for (int mt = 0; mt < 8; ++mt) {
    f32x4 aI[NG], aC[NG], aO[NG];
#pragma unroll
    for (int g = 0; g < NG; ++g) { aI[g] = z; aC[g] = z; aO[g] = z; }
#pragma unroll
    for (int ks = 0; ks < 2; ++ks) {
      const int off = ((ks * 32 + q * 8) ^ sw1);
      short8 fI = *(const short8*)&w1s[(mt * 16 + col) * ISZ + off];
      short8 fC = *(const short8*)&w1s[(128 + mt * 16 + col) * ISZ + off];
      short8 fO = *(const short8*)&w1s[(256 + mt * 16 + col) * ISZ + off];
#pragma unroll
      for (int g = 0; g < NG; ++g) {
        aI[g] = __builtin_amdgcn_mfma_f32_16x16x32_bf16(fI, xf[g][ks], aI[g], 0, 0, 0);
        aC[g] = __builtin_amdgcn_mfma_f32_16x16x32_bf16(fC, xf[g][ks], aC[g], 0, 0, 0);
        aO[g] = __builtin_amdgcn_mfma_f32_16x16x32_bf16(fO, xf[g][ks], aO[g], 0, 0, 0);
      }
    }
    float bI[4], bC[4], bO[4];
#pragma unroll
    for (int r = 0; r < 4; ++r) {
      const int h = mt * 16 + q * 4 + r;   // buffer row (permuted bs1 matches)
      bI[r] = bs1[h]; bC[r] = bs1[256 + h]; bO[r] = bs1[384 + h];
    }
#pragma unroll
    for (int g = 0; g < NG; ++g) {
      u16 hv[4];
#pragma unroll
      for (int r = 0; r < 4; ++r) {
        float c = gate2(aI[g][r] + bI[r], aC[g][r] + bC[r]);
        hv[r] = f2bf(gate2(aO[g][r] + bO[r], TWOLOG2E * c));
      }
      pk[g][mt][0] = (uint32_t)hv[0] | ((uint32_t)hv[1] << 16);
      pk[g][mt][1] = (uint32_t)hv[2] | ((uint32_t)hv[3] << 16);
    }
  }

  // ---- h1 fragments: pure register rename (R6-verified)
  short8 hf[NG][4];
#pragma unroll
  for (int g = 0; g < NG; ++g)
#pragma unroll
    for (int ks = 0; ks < 4; ++ks)
      hf[g][ks] = mk8(pk[g][ks][0], pk[g][ks][1], pk[g][ks + 4][0], pk[g][ks + 4][1]);

  // ---- LSTM layer 2 (K=128); h2 stays in registers (pk2)
  uint32_t pk2[NG][8][2];
#pragma unroll
  for (int mt = 0; mt < 8; ++mt) {
    f32x4 aI[NG], aC[NG], aO[NG];
#pragma unroll
    for (int g = 0; g < NG; ++g) { aI[g] = z; aC[g] = z; aO[g] = z; }
#pragma unroll
    for (int ks = 0; ks < 4; ++ks) {
      const int off = ((ks * 32 + q * 8) ^ sw2);
      short8 fI = *(const short8*)&w2s[(mt * 16 + col) * HSZ + off];
      short8 fC = *(const short8*)&w2s[(128 + mt * 16 + col) * HSZ + off];
      short8 fO = *(const short8*)&w2s[(256 + mt * 16 + col) * HSZ + off];
#pragma unroll
      for (int g = 0; g < NG; ++g) {
        aI[g] = __builtin_amdgcn_mfma_f32_16x16x32_bf16(fI, hf[g][ks], aI[g], 0, 0, 0);
        aC[g] = __builtin_amdgcn_mfma_f32_16x16x32_bf16(fC, hf[g][ks], aC[g], 0, 0, 0);
        aO[g] = __builtin_amdgcn_mfma_f32_16x16x32_bf16(fO, hf[g][ks], aO[g], 0, 0, 0);
      }
    }
    float bI[4], bC[4], bO[4];
#pragma unroll
    for (int r = 0; r < 4; ++r) {
      const int h = mt * 16 + q * 4 + r;
      bI[r] = bs2[h]; bC[r] = bs2[256 + h]; bO[r] = bs2[384 + h];
    }
#pragma unroll
    for (int g = 0; g < NG; ++g) {
      u16 hv[4];
#pragma unroll
      for (int r = 0; r < 4; ++r) {
        float c = gate2(aI[g][r] + bI[r], aC[g][r] + bC[r]);
        hv[r] = f2bf(gate2(aO[g][r] + bO[r], TWOLOG2E * c));
      }
      pk2[g][mt][0] = (uint32_t)hv[0] | ((uint32_t)hv[1] << 16);
      pk2[g][mt][1] = (uint32_t)hv[2] | ((uint32_t)hv[3] << 16);
    }
  }

  // ---- h2 fragments (linear-k) via rename (R6-verified)
  short8 hf2[NG][4];
#pragma unroll
  for (int g = 0; g < NG; ++g)
#pragma unroll
    for (int ks = 0; ks < 4; ++ks)
      hf2[g][ks] = mk8(pk2[g][ks][0], pk2[g][ks][1], pk2[g][ks + 4][0], pk2[g][ks + 4][1]);

  // ---- attention-MLP energy (R6 verbatim; wp1 stays global)
  float ep[NG];
#pragma unroll
  for (int g = 0; g < NG; ++g) ep[g] = 0.f;
#pragma unroll
  for (int mt = 0; mt < 4; ++mt) {
    f32x4 acc[NG];
#pragma unroll
    for (int g = 0; g < NG; ++g) acc[g] = z;
#pragma unroll
    for (int ks = 0; ks < 4; ++ks) {
      short8 fA = *(const short8*)(wp1b + (size_t)(mt * 16 + col) * HSZ + ks * 32 + q * 8);
#pragma unroll
      for (int g = 0; g < NG; ++g)
        acc[g] = __builtin_amdgcn_mfma_f32_16x16x32_bf16(fA, hf2[g][ks], acc[g], 0, 0, 0);
    }
#pragma unroll
    for (int r = 0; r < 4; ++r) {
      const int hp = mt * 16 + q * 4 + r;
      const float b1 = bp1v[hp];
      const float w2 = Wp2[hp];
#pragma unroll
      for (int g = 0; g < NG; ++g)
        ep[g] += fmaxf(acc[g][r] + b1, 0.f) * w2;
    }
  }
#pragma unroll
  for (int g = 0; g < NG; ++g) {
    ep[g] += __shfl_xor(ep[g], 16);
    ep[g] += __shfl_xor(ep[g], 32);
  }
  const float bp2f = bp2v[0];

  // ---- masked softmax (R6 verbatim; token l = g*16 + col)
  float e[NG]; bool val[NG];
  float m = -3.0e38f;
#pragma unroll
  for (int g = 0; g < NG; ++g) {
    val[g] = (g * 16 + col) < len;
    e[g] = ep[g] + bp2f;
    m = fmaxf(m, val[g] ? e[g] : -3.0e38f);
  }
  m = fmaxf(m, __shfl_xor(m, 1));
  m = fmaxf(m, __shfl_xor(m, 2));
  m = fmaxf(m, __shfl_xor(m, 4));
  m = fmaxf(m, __shfl_xor(m, 8));
  float wgt[NG], s = 0.f;
#pragma unroll
  for (int g = 0; g < NG; ++g) {
    wgt[g] = val[g] ? __expf(e[g] - m) : 0.f;
    s += wgt[g];
  }
  s += __shfl_xor(s, 1);
  s += __shfl_xor(s, 2);
  s += __shfl_xor(s, 4);
  s += __shfl_xor(s, 8);
  const float inv = __builtin_amdgcn_rcpf(s);

  // ---- in-register weighted sum (R8-verified)
  float ta[4][8];
#pragma unroll
  for (int ks = 0; ks < 4; ++ks)
#pragma unroll
    for (int j = 0; j < 8; ++j) ta[ks][j] = 0.f;
#pragma unroll
  for (int g = 0; g < NG; ++g) {
    const float wl = wgt[g] * inv;
#pragma unroll
    for (int ks = 0; ks < 4; ++ks) {
      union { short8 s; uint32_t u[4]; } zz;
      zz.s = hf2[g][ks];
#pragma unroll
      for (int w = 0; w < 4; ++w) {
        ta[ks][2 * w]     += wl * bflo(zz.u[w]);
        ta[ks][2 * w + 1] += wl * bfhi(zz.u[w]);
      }
    }
  }
  // col-butterfly: sum over 16 tokens (q-groups hold disjoint h)
#pragma unroll
  for (int ks = 0; ks < 4; ++ks)
#pragma unroll
    for (int j = 0; j < 8; ++j) {
      float v = ta[ks][j];
      v += __shfl_xor(v, 1);
      v += __shfl_xor(v, 2);
      v += __shfl_xor(v, 4);
      v += __shfl_xor(v, 8);
      ta[ks][j] = v;
    }
  // scatter: exactly one lane per h = ks*32+q*8+j (col = ks*2+(j>>2))
#pragma unroll
  for (int ks = 0; ks < 4; ++ks)
#pragma unroll
    for (int j = 0; j < 8; ++j)
      if (col == ks * 2 + (j >> 2))
        atomicAdd(&bin[ks * 32 + q * 8 + j], ta[ks][j]);
}

// ---------------------------------------------------------------------------
// k_fused: 16 waves (1024 thr) per block, grid 256 = 1 block/CU; 144 KB LDS
// weight image shared by 16 waves = 4 waves/SIMD.
// __launch_bounds__(1024, 4): the 2nd arg (min waves per EU) pins the VGPR
// budget at 512/4 = 128 — exactly what the R11 body allocates naturally.
// R12's bare (1024) let the default waves-per-EU heuristic target 64 VGPR
// and spill (42+89 MB scratch traffic, dur 113us).
// ---------------------------------------------------------------------------
__global__ __launch_bounds__(1024, 4) void k_fused(
    const u16* __restrict__ embb,
    const u16* __restrict__ w1b, const float* __restrict__ bs1,
    const u16* __restrict__ w2b, const float* __restrict__ bs2,
    const u16* __restrict__ wp1b,
    const float* __restrict__ bp1v, const float* __restrict__ Wp2,
    const float* __restrict__ bp2v,
    const int* __restrict__ traces, const int* __restrict__ lengths,
    float* __restrict__ bins)
{
  __shared__ __align__(16) u16 w1s[384 * 64];    //  48 KB
  __shared__ __align__(16) u16 w2s[384 * 128];   //  96 KB
  const int tid = threadIdx.x;

  // ---- stage w1 (384 rows x 64 u16 = 3072 uint4), compact + swizzle
  for (int i = tid; i < 3072; i += 1024) {
    const int r = i >> 3;
    const int src = (r < 128) ? r : r + 128;     // skip f-gate rows
    const int c16 = (i & 7) * 8;
    *(u32x4*)&w1s[r * 64 + (c16 ^ ((r & 7) << 3))] =
        *(const u32x4*)&w1b[src * 64 + c16];
  }
  // ---- stage w2 (384 rows x 128 u16 = 6144 uint4)
  for (int i = tid; i < 6144; i += 1024) {
    const int r = i >> 4;
    const int src = (r < 128) ? r : r + 128;
    const int c16 = (i & 15) * 8;
    *(u32x4*)&w2s[r * 128 + (c16 ^ ((r & 15) << 3))] =
        *(const u32x4*)&w2b[src * 128 + c16];
  }
  __syncthreads();

  const int wv = tid >> 6;                       // wave id 0..15
  const int t  = blockIdx.x * 16 + wv;
  const int len = lengths[t];
  const int ngrp = (len + 15) >> 4;
  float* bin = bins + (size_t)(t & (NBIN - 1)) * HSZ;
  switch (ngrp) {
    case 1: trace_body<1>(embb, w1s, bs1, w2s, bs2, wp1b,
                          bp1v, Wp2, bp2v, traces, bin, t, len); break;
    case 2: trace_body<2>(embb, w1s, bs1, w2s, bs2, wp1b,
                          bp1v, Wp2, bp2v, traces, bin, t, len); break;
    case 3: trace_body<3>(embb, w1s, bs1, w2s, bs2, wp1b,
                          bp1v, Wp2, bp2v, traces, bin, t, len); break;
    default: trace_body<4>(embb, w1s, bs1, w2s, bs2, wp1b,
                           bp1v, Wp2, bp2v, traces, bin, t, len); break;
  }
}

// ---------------------------------------------------------------------------
// k_out (R6-VERIFIED, verbatim): reduce 64 bins -> fin, then 128x128 matvec.
// ---------------------------------------------------------------------------
__global__ __launch_bounds__(128) void k_out(
    const float* __restrict__ bins, const float* __restrict__ W_out,
    const float* __restrict__ b_out, float* __restrict__ out)
{
  const int o = threadIdx.x;      // 0..127
  __shared__ float fs[HSZ];
  float s = 0.f;
#pragma unroll 4
  for (int b = 0; b < NBIN; ++b) s += bins[b * HSZ + o];
  fs[o] = s;
  __syncthreads();
  float acc = b_out[o];
  const float* wr = W_out + (size_t)o * HSZ;
#pragma unroll
  for (int h = 0; h < HSZ; ++h) acc += wr[h] * fs[h];
  out[o] = acc;
}

extern "C" void kernel_launch(void* const* d_in, const int* in_sizes, int n_in,
                              void* d_out, int out_size, void* d_ws, size_t ws_size,
                              hipStream_t stream)
{
  const float* emb   = (const float*)d_in[0];
  const float* W_ih1 = (const float*)d_in[1];
  // d_in[2] = W_hh1: unused (h0 = 0)
  const float* b_ih1 = (const float*)d_in[3];
  const float* b_hh1 = (const float*)d_in[4];
  const float* W_ih2 = (const float*)d_in[5];
  // d_in[6] = W_hh2: unused
  const float* b_ih2 = (const float*)d_in[7];
  const float* b_hh2 = (const float*)d_in[8];
  const float* Wp1   = (const float*)d_in[9];
  const float* bp1   = (const float*)d_in[10];
  const float* Wp2   = (const float*)d_in[11];
  const float* bp2   = (const float*)d_in[12];
  const float* W_out = (const float*)d_in[13];
  const float* b_out = (const float*)d_in[14];
  const int* traces  = (const int*)d_in[15];
  const int* lengths = (const int*)d_in[16];

  char* ws = (char*)d_ws;
  u16*   w1b  = (u16*)(ws);                  // 512*64*2   = 65536 B
  u16*   w2b  = (u16*)(ws + 65536);          // 512*128*2  = 131072 B
  u16*   wp1b = (u16*)(ws + 196608);         // 64*128*2   = 16384 B
  float* bs1  = (float*)(ws + 212992);       // 2048 B
  float* bs2  = (float*)(ws + 215040);       // 2048 B
  float* bins = (float*)(ws + 217088);       // 64*128*4   = 32768 B
  u16*   embb = (u16*)(ws + 249856);         // 10000*64*2 = 1280000 B

  k_prep<<<256, 256, 0, stream>>>(emb, W_ih1, W_ih2, Wp1, b_ih1, b_hh1,
                                  b_ih2, b_hh2, embb, w1b, w2b, wp1b,
                                  bs1, bs2, bins);
  k_fused<<<NTRACE / 16, 1024, 0, stream>>>(embb, w1b, bs1, w2b, bs2, wp1b,
                                            bp1, Wp2, bp2, traces, lengths, bins);
  k_out<<<1, 128, 0, stream>>>(bins, W_out, b_out, (float*)d_out);
}

// Round 14
// 202.535 us; speedup vs baseline: 1.0021x; 1.0021x over previous
//
#include <hip/hip_runtime.h>
#include <stdint.h>

typedef unsigned short u16;
typedef __attribute__((ext_vector_type(8))) short short8;
typedef __attribute__((ext_vector_type(4))) float f32x4;
typedef __attribute__((ext_vector_type(4))) unsigned int u32x4;

#define NTRACE 4096
#define TLEN   64
#define ISZ    64
#define HSZ    128
#define NBIN   64

#define LOG2E     1.44269504088896f
#define TWOLOG2E  2.88539008177793f

__device__ __forceinline__ float bflo(uint32_t u) {
  union { uint32_t i; float f; } v; v.i = u << 16; return v.f;
}
__device__ __forceinline__ float bfhi(uint32_t u) {
  union { uint32_t i; float f; } v; v.i = u & 0xffff0000u; return v.f;
}
__device__ __forceinline__ u16 f2bf(float f) {
  union { float f; uint32_t i; } v; v.f = f;
  uint32_t r = v.i + 0x7fffu + ((v.i >> 16) & 1u);
  return (u16)(r >> 16);
}
__device__ __forceinline__ float fexp2(float x) {
  float r;
  asm("v_exp_f32 %0, %1" : "=v"(r) : "v"(x));
  return r;
}
// tanh(a)*sigmoid(b) with pre-scaled gates: gB=-log2e*b, gE=2log2e*a
__device__ __forceinline__ float gate2(float gB, float gE) {
  float E = fexp2(gE);
  float B = fexp2(gB);
  return (E - 1.0f) * __builtin_amdgcn_rcpf((E + 1.0f) * (1.0f + B));
}
__device__ __forceinline__ short8 mk8(uint32_t a, uint32_t b, uint32_t c, uint32_t d) {
  union { short8 s; uint32_t u[4]; } z;
  z.u[0] = a; z.u[1] = b; z.u[2] = c; z.u[3] = d; return z.s;
}
// Weight-row permutation (R6-VERIFIED): buffer tile-row rr holds true hidden
// index pi(rr); MFMA C output renames register-only into the next layer's
// B-fragment (linear k): frag ks elem j = h[ks*32+q*8+j].
__device__ __forceinline__ int perm128(int rr) {
  return ((rr >> 4) & 3) * 32 + ((rr >> 2) & 3) * 8 + ((rr >> 6) & 1) * 4 + (rr & 3);
}

// ---------------------------------------------------------------------------
// k_prep (R6-VERIFIED, verbatim): bf16 weights with exp2 scale folding + pi
// row permutation; emb->bf16; bins zero.
// ---------------------------------------------------------------------------
__global__ __launch_bounds__(256) void k_prep(
    const float* __restrict__ emb,
    const float* __restrict__ W1, const float* __restrict__ W2,
    const float* __restrict__ Wp1,
    const float* __restrict__ b_ih1, const float* __restrict__ b_hh1,
    const float* __restrict__ b_ih2, const float* __restrict__ b_hh2,
    u16* __restrict__ embb,
    u16* __restrict__ w1b, u16* __restrict__ w2b, u16* __restrict__ wp1b,
    float* __restrict__ bs1, float* __restrict__ bs2,
    float* __restrict__ bins)
{
  const int i = blockIdx.x * 256 + threadIdx.x;   // 65536 threads
  if (i < 512 * 64) {
    const int row = i >> 6, G = row >> 7, rr = row & 127;
    const float s = (G == 2) ? TWOLOG2E : -LOG2E;
    w1b[i] = f2bf(W1[(G * 128 + perm128(rr)) * ISZ + (i & 63)] * s);
  }
  if (i < 512 * 128) {
    const int row = i >> 7, G = row >> 7, rr = row & 127;
    const float s = (G == 2) ? TWOLOG2E : -LOG2E;
    w2b[i] = f2bf(W2[(G * 128 + perm128(rr)) * HSZ + (i & 127)] * s);
  }
  if (i < 64 * 128) wp1b[i] = f2bf(Wp1[i]);
  if (i < 512) {
    const int G = i >> 7, rr = i & 127;
    const float s = (G == 2) ? TWOLOG2E : -LOG2E;
    const int src = G * 128 + perm128(rr);
    bs1[i] = (b_ih1[src] + b_hh1[src]) * s;
    bs2[i] = (b_ih2[src] + b_hh2[src]) * s;
  }
  if (i < NBIN * HSZ) bins[i] = 0.f;
  for (int j = i; j < 10000 * 64; j += 256 * 256) embb[j] = f2bf(emb[j]);
}

// ---------------------------------------------------------------------------
// trace_body<NG> (R11-VERIFIED, verbatim): one wave, one trace, fully in
// registers (pi rename); w1/w2 from LDS (compact i@0/g@128/o@256 rows,
// XOR-swizzled); single-shot softmax; in-register weighted sum;
// col-butterfly; one-lane-per-h scatter into bin.
// ---------------------------------------------------------------------------
template<int NG>
__device__ __forceinline__ void trace_body(
    const u16* __restrict__ embb,
    const u16* w1s, const float* __restrict__ bs1,
    const u16* w2s, const float* __restrict__ bs2,
    const u16* __restrict__ wp1b,
    const float* __restrict__ bp1v, const float* __restrict__ Wp2,
    const float* __restrict__ bp2v,
    const int* __restrict__ traces,
    float* __restrict__ bin, int t, int len)
{
  const int lane = threadIdx.x & 63;
  const int col  = lane & 15;
  const int q    = lane >> 4;
  const int sw1  = (col & 7) << 3;   // w1 read XOR (u16 units)
  const int sw2  = col << 3;         // w2 read XOR (u16 units)
  const f32x4 z = {0.f, 0.f, 0.f, 0.f};

  // ---- x fragments (bf16 emb, B-operand of lstm1)
  short8 xf[NG][2];
#pragma unroll
  for (int g = 0; g < NG; ++g) {
    const int tok = traces[t * TLEN + g * 16 + col];
    const u16* xr = embb + (size_t)tok * ISZ + q * 8;
    xf[g][0] = *(const short8*)(xr);
    xf[g][1] = *(const short8*)(xr + 32);
  }

  // ---- LSTM layer 1 (K=64); LDS compact rows: i@0, g@128, o@256
  uint32_t pk[NG][8][2];
#pragma unroll
  for (int mt = 0; mt < 8; ++mt) {
    f32x4 aI[NG], aC[NG], aO[NG];
#pragma unroll
    for (int g = 0; g < NG; ++g) { aI[g] = z; aC[g] = z; aO[g] = z; }
#pragma unroll
    for (int ks = 0; ks < 2; ++ks) {
      const int off = ((ks * 32 + q * 8) ^ sw1);
      short8 fI = *(const short8*)&w1s[(mt * 16 + col) * ISZ + off];
      short8 fC = *(const short8*)&w1s[(128 + mt * 16 + col) * ISZ + off];
      short8 fO = *(const short8*)&w1s[(256 + mt * 16 + col) * ISZ + off];
#pragma unroll
      for (int g = 0; g < NG; ++g) {
        aI[g] = __builtin_amdgcn_mfma_f32_16x16x32_bf16(fI, xf[g][ks], aI[g], 0, 0, 0);
        aC[g] = __builtin_amdgcn_mfma_f32_16x16x32_bf16(fC, xf[g][ks], aC[g], 0, 0, 0);
        aO[g] = __builtin_amdgcn_mfma_f32_16x16x32_bf16(fO, xf[g][ks], aO[g], 0, 0, 0);
      }
    }
    float bI[4], bC[4], bO[4];
#pragma unroll
    for (int r = 0; r < 4; ++r) {
      const int h = mt * 16 + q * 4 + r;   // buffer row (permuted bs1 matches)
      bI[r] = bs1[h]; bC[r] = bs1[256 + h]; bO[r] = bs1[384 + h];
    }
#pragma unroll
    for (int g = 0; g < NG; ++g) {
      u16 hv[4];
#pragma unroll
      for (int r = 0; r < 4; ++r) {
        float c = gate2(aI[g][r] + bI[r], aC[g][r] + bC[r]);
        hv[r] = f2bf(gate2(aO[g][r] + bO[r], TWOLOG2E * c));
      }
      pk[g][mt][0] = (uint32_t)hv[0] | ((uint32_t)hv[1] << 16);
      pk[g][mt][1] = (uint32_t)hv[2] | ((uint32_t)hv[3] << 16);
    }
  }

  // ---- h1 fragments: pure register rename (R6-verified)
  short8 hf[NG][4];
#pragma unroll
  for (int g = 0; g < NG; ++g)
#pragma unroll
    for (int ks = 0; ks < 4; ++ks)
      hf[g][ks] = mk8(pk[g][ks][0], pk[g][ks][1], pk[g][ks + 4][0], pk[g][ks + 4][1]);

  // ---- LSTM layer 2 (K=128); h2 stays in registers (pk2)
  uint32_t pk2[NG][8][2];
#pragma unroll
  for (int mt = 0; mt < 8; ++mt) {
    f32x4 aI[NG], aC[NG], aO[NG];
#pragma unroll
    for (int g = 0; g < NG; ++g) { aI[g] = z; aC[g] = z; aO[g] = z; }
#pragma unroll
    for (int ks = 0; ks < 4; ++ks) {
      const int off = ((ks * 32 + q * 8) ^ sw2);
      short8 fI = *(const short8*)&w2s[(mt * 16 + col) * HSZ + off];
      short8 fC = *(const short8*)&w2s[(128 + mt * 16 + col) * HSZ + off];
      short8 fO = *(const short8*)&w2s[(256 + mt * 16 + col) * HSZ + off];
#pragma unroll
      for (int g = 0; g < NG; ++g) {
        aI[g] = __builtin_amdgcn_mfma_f32_16x16x32_bf16(fI, hf[g][ks], aI[g], 0, 0, 0);
        aC[g] = __builtin_amdgcn_mfma_f32_16x16x32_bf16(fC, hf[g][ks], aC[g], 0, 0, 0);
        aO[g] = __builtin_amdgcn_mfma_f32_16x16x32_bf16(fO, hf[g][ks], aO[g], 0, 0, 0);
      }
    }
    float bI[4], bC[4], bO[4];
#pragma unroll
    for (int r = 0; r < 4; ++r) {
      const int h = mt * 16 + q * 4 + r;
      bI[r] = bs2[h]; bC[r] = bs2[256 + h]; bO[r] = bs2[384 + h];
    }
#pragma unroll
    for (int g = 0; g < NG; ++g) {
      u16 hv[4];
#pragma unroll
      for (int r = 0; r < 4; ++r) {
        float c = gate2(aI[g][r] + bI[r], aC[g][r] + bC[r]);
        hv[r] = f2bf(gate2(aO[g][r] + bO[r], TWOLOG2E * c));
      }
      pk2[g][mt][0] = (uint32_t)hv[0] | ((uint32_t)hv[1] << 16);
      pk2[g][mt][1] = (uint32_t)hv[2] | ((uint32_t)hv[3] << 16);
    }
  }

  // ---- h2 fragments (linear-k) via rename (R6-verified)
  short8 hf2[NG][4];
#pragma unroll
  for (int g = 0; g < NG; ++g)
#pragma unroll
    for (int ks = 0; ks < 4; ++ks)
      hf2[g][ks] = mk8(pk2[g][ks][0], pk2[g][ks][1], pk2[g][ks + 4][0], pk2[g][ks + 4][1]);

  // ---- attention-MLP energy (R6 verbatim; wp1 stays global)
  float ep[NG];
#pragma unroll
  for (int g = 0; g < NG; ++g) ep[g] = 0.f;
#pragma unroll
  for (int mt = 0; mt < 4; ++mt) {
    f32x4 acc[NG];
#pragma unroll
    for (int g = 0; g < NG; ++g) acc[g] = z;
#pragma unroll
    for (int ks = 0; ks < 4; ++ks) {
      short8 fA = *(const short8*)(wp1b + (size_t)(mt * 16 + col) * HSZ + ks * 32 + q * 8);
#pragma unroll
      for (int g = 0; g < NG; ++g)
        acc[g] = __builtin_amdgcn_mfma_f32_16x16x32_bf16(fA, hf2[g][ks], acc[g], 0, 0, 0);
    }
#pragma unroll
    for (int r = 0; r < 4; ++r) {
      const int hp = mt * 16 + q * 4 + r;
      const float b1 = bp1v[hp];
      const float w2 = Wp2[hp];
#pragma unroll
      for (int g = 0; g < NG; ++g)
        ep[g] += fmaxf(acc[g][r] + b1, 0.f) * w2;
    }
  }
#pragma unroll
  for (int g = 0; g < NG; ++g) {
    ep[g] += __shfl_xor(ep[g], 16);
    ep[g] += __shfl_xor(ep[g], 32);
  }
  const float bp2f = bp2v[0];

  // ---- masked softmax (R6 verbatim; token l = g*16 + col)
  float e[NG]; bool val[NG];
  float m = -3.0e38f;
#pragma unroll
  for (int g = 0; g < NG; ++g) {
    val[g] = (g * 16 + col) < len;
    e[g] = ep[g] + bp2f;
    m = fmaxf(m, val[g] ? e[g] : -3.0e38f);
  }
  m = fmaxf(m, __shfl_xor(m, 1));
  m = fmaxf(m, __shfl_xor(m, 2));
  m = fmaxf(m, __shfl_xor(m, 4));
  m = fmaxf(m, __shfl_xor(m, 8));
  float wgt[NG], s = 0.f;
#pragma unroll
  for (int g = 0; g < NG; ++g) {
    wgt[g] = val[g] ? __expf(e[g] - m) : 0.f;
    s += wgt[g];
  }
  s += __shfl_xor(s, 1);
  s += __shfl_xor(s, 2);
  s += __shfl_xor(s, 4);
  s += __shfl_xor(s, 8);
  const float inv = __builtin_amdgcn_rcpf(s);

  // ---- in-register weighted sum (R8-verified)
  float ta[4][8];
#pragma unroll
  for (int ks = 0; ks < 4; ++ks)
#pragma unroll
    for (int j = 0; j < 8; ++j) ta[ks][j] = 0.f;
#pragma unroll
  for (int g = 0; g < NG; ++g) {
    const float wl = wgt[g] * inv;
#pragma unroll
    for (int ks = 0; ks < 4; ++ks) {
      union { short8 s; uint32_t u[4]; } zz;
      zz.s = hf2[g][ks];
#pragma unroll
      for (int w = 0; w < 4; ++w) {
        ta[ks][2 * w]     += wl * bflo(zz.u[w]);
        ta[ks][2 * w + 1] += wl * bfhi(zz.u[w]);
      }
    }
  }
  // col-butterfly: sum over 16 tokens (q-groups hold disjoint h)
#pragma unroll
  for (int ks = 0; ks < 4; ++ks)
#pragma unroll
    for (int j = 0; j < 8; ++j) {
      float v = ta[ks][j];
      v += __shfl_xor(v, 1);
      v += __shfl_xor(v, 2);
      v += __shfl_xor(v, 4);
      v += __shfl_xor(v, 8);
      ta[ks][j] = v;
    }
  // scatter: exactly one lane per h = ks*32+q*8+j (col = ks*2+(j>>2))
#pragma unroll
  for (int ks = 0; ks < 4; ++ks)
#pragma unroll
    for (int j = 0; j < 8; ++j)
      if (col == ks * 2 + (j >> 2))
        atomicAdd(&bin[ks * 32 + q * 8 + j], ta[ks][j]);
}

// ---------------------------------------------------------------------------
// k_fused: 16 waves (1024 thr) per block, grid 256 = 1 block/CU; 144 KB LDS
// weight image shared by 16 waves = 4 waves/SIMD.
// amdgpu_waves_per_eu(4, 4): the MAX=4 is the operative part — it forces the
// VGPR budget to 512/4 = 128. __launch_bounds__'s 2nd arg only sets MIN
// waves/EU, which one resident 16-wave block satisfies at ANY vgpr count,
// so R12/R13's allocator kept targeting 8 waves/EU -> 64 VGPR -> spills
// (42+89 MB scratch traffic, slow scratch-alloc first dispatch).
// ---------------------------------------------------------------------------
__global__
__attribute__((amdgpu_flat_work_group_size(1024, 1024), amdgpu_waves_per_eu(4, 4)))
void k_fused(
    const u16* __restrict__ embb,
    const u16* __restrict__ w1b, const float* __restrict__ bs1,
    const u16* __restrict__ w2b, const float* __restrict__ bs2,
    const u16* __restrict__ wp1b,
    const float* __restrict__ bp1v, const float* __restrict__ Wp2,
    const float* __restrict__ bp2v,
    const int* __restrict__ traces, const int* __restrict__ lengths,
    float* __restrict__ bins)
{
  __shared__ __align__(16) u16 w1s[384 * 64];    //  48 KB
  __shared__ __align__(16) u16 w2s[384 * 128];   //  96 KB
  const int tid = threadIdx.x;

  // ---- stage w1 (384 rows x 64 u16 = 3072 uint4), compact + swizzle
  for (int i = tid; i < 3072; i += 1024) {
    const int r = i >> 3;
    const int src = (r < 128) ? r : r + 128;     // skip f-gate rows
    const int c16 = (i & 7) * 8;
    *(u32x4*)&w1s[r * 64 + (c16 ^ ((r & 7) << 3))] =
        *(const u32x4*)&w1b[src * 64 + c16];
  }
  // ---- stage w2 (384 rows x 128 u16 = 6144 uint4)
  for (int i = tid; i < 6144; i += 1024) {
    const int r = i >> 4;
    const int src = (r < 128) ? r : r + 128;
    const int c16 = (i & 15) * 8;
    *(u32x4*)&w2s[r * 128 + (c16 ^ ((r & 15) << 3))] =
        *(const u32x4*)&w2b[src * 128 + c16];
  }
  __syncthreads();

  const int wv = tid >> 6;                       // wave id 0..15
  const int t  = blockIdx.x * 16 + wv;
  const int len = lengths[t];
  const int ngrp = (len + 15) >> 4;
  float* bin = bins + (size_t)(t & (NBIN - 1)) * HSZ;
  switch (ngrp) {
    case 1: trace_body<1>(embb, w1s, bs1, w2s, bs2, wp1b,
                          bp1v, Wp2, bp2v, traces, bin, t, len); break;
    case 2: trace_body<2>(embb, w1s, bs1, w2s, bs2, wp1b,
                          bp1v, Wp2, bp2v, traces, bin, t, len); break;
    case 3: trace_body<3>(embb, w1s, bs1, w2s, bs2, wp1b,
                          bp1v, Wp2, bp2v, traces, bin, t, len); break;
    default: trace_body<4>(embb, w1s, bs1, w2s, bs2, wp1b,
                           bp1v, Wp2, bp2v, traces, bin, t, len); break;
  }
}

// ---------------------------------------------------------------------------
// k_out (R6-VERIFIED, verbatim): reduce 64 bins -> fin, then 128x128 matvec.
// ---------------------------------------------------------------------------
__global__ __launch_bounds__(128) void k_out(
    const float* __restrict__ bins, const float* __restrict__ W_out,
    const float* __restrict__ b_out, float* __restrict__ out)
{
  const int o = threadIdx.x;      // 0..127
  __shared__ float fs[HSZ];
  float s = 0.f;
#pragma unroll 4
  for (int b = 0; b < NBIN; ++b) s += bins[b * HSZ + o];
  fs[o] = s;
  __syncthreads();
  float acc = b_out[o];
  const float* wr = W_out + (size_t)o * HSZ;
#pragma unroll
  for (int h = 0; h < HSZ; ++h) acc += wr[h] * fs[h];
  out[o] = acc;
}

extern "C" void kernel_launch(void* const* d_in, const int* in_sizes, int n_in,
                              void* d_out, int out_size, void* d_ws, size_t ws_size,
                              hipStream_t stream)
{
  const float* emb   = (const float*)d_in[0];
  const float* W_ih1 = (const float*)d_in[1];
  // d_in[2] = W_hh1: unused (h0 = 0)
  const float* b_ih1 = (const float*)d_in[3];
  const float* b_hh1 = (const float*)d_in[4];
  const float* W_ih2 = (const float*)d_in[5];
  // d_in[6] = W_hh2: unused
  const float* b_ih2 = (const float*)d_in[7];
  const float* b_hh2 = (const float*)d_in[8];
  const float* Wp1   = (const float*)d_in[9];
  const float* bp1   = (const float*)d_in[10];
  const float* Wp2   = (const float*)d_in[11];
  const float* bp2   = (const float*)d_in[12];
  const float* W_out = (const float*)d_in[13];
  const float* b_out = (const float*)d_in[14];
  const int* traces  = (const int*)d_in[15];
  const int* lengths = (const int*)d_in[16];

  char* ws = (char*)d_ws;
  u16*   w1b  = (u16*)(ws);                  // 512*64*2   = 65536 B
  u16*   w2b  = (u16*)(ws + 65536);          // 512*128*2  = 131072 B
  u16*   wp1b = (u16*)(ws + 196608);         // 64*128*2   = 16384 B
  float* bs1  = (float*)(ws + 212992);       // 2048 B
  float* bs2  = (float*)(ws + 215040);       // 2048 B
  float* bins = (float*)(ws + 217088);       // 64*128*4   = 32768 B
  u16*   embb = (u16*)(ws + 249856);         // 10000*64*2 = 1280000 B

  k_prep<<<256, 256, 0, stream>>>(emb, W_ih1, W_ih2, Wp1, b_ih1, b_hh1,
                                  b_ih2, b_hh2, embb, w1b, w2b, wp1b,
                                  bs1, bs2, bins);
  k_fused<<<NTRACE / 16, 1024, 0, stream>>>(embb, w1b, bs1, w2b, bs2, wp1b,
                                            bp1, Wp2, bp2, traces, lengths, bins);
  k_out<<<1, 128, 0, stream>>>(bins, W_out, b_out, (float*)d_out);
}

// Round 15
// 144.170 us; speedup vs baseline: 1.4078x; 1.4048x over previous
//
#include <hip/hip_runtime.h>
#include <stdint.h>

typedef unsigned short u16;
typedef __attribute__((ext_vector_type(8))) short short8;
typedef __attribute__((ext_vector_type(4))) float f32x4;
typedef __attribute__((ext_vector_type(4))) unsigned int u32x4;

#define NTRACE 4096
#define TLEN   64
#define ISZ    64
#define HSZ    128
#define NBIN   64
#define VSZ    10000

#define LOG2E     1.44269504088896f
#define TWOLOG2E  2.88539008177793f

__device__ __forceinline__ float bflo(uint32_t u) {
  union { uint32_t i; float f; } v; v.i = u << 16; return v.f;
}
__device__ __forceinline__ float bfhi(uint32_t u) {
  union { uint32_t i; float f; } v; v.i = u & 0xffff0000u; return v.f;
}
__device__ __forceinline__ u16 f2bf(float f) {
  union { float f; uint32_t i; } v; v.f = f;
  uint32_t r = v.i + 0x7fffu + ((v.i >> 16) & 1u);
  return (u16)(r >> 16);
}
__device__ __forceinline__ float fexp2(float x) {
  float r;
  asm("v_exp_f32 %0, %1" : "=v"(r) : "v"(x));
  return r;
}
// tanh(a)*sigmoid(b) with pre-scaled gates: gB=-log2e*b, gE=2log2e*a
__device__ __forceinline__ float gate2(float gB, float gE) {
  float E = fexp2(gE);
  float B = fexp2(gB);
  return (E - 1.0f) * __builtin_amdgcn_rcpf((E + 1.0f) * (1.0f + B));
}
__device__ __forceinline__ short8 mk8(uint32_t a, uint32_t b, uint32_t c, uint32_t d) {
  union { short8 s; uint32_t u[4]; } z;
  z.u[0] = a; z.u[1] = b; z.u[2] = c; z.u[3] = d; return z.s;
}
// Weight-row permutation (R6-VERIFIED): buffer tile-row rr holds true hidden
// index pi(rr); MFMA C output renames register-only into the next layer's
// B-fragment (linear k): frag ks elem j = h[ks*32+q*8+j].
__device__ __forceinline__ int perm128(int rr) {
  return ((rr >> 4) & 3) * 32 + ((rr >> 2) & 3) * 8 + ((rr >> 6) & 1) * 4 + (rr & 3);
}

// ---------------------------------------------------------------------------
// k_prep (R6-VERIFIED, verbatim): bf16 weights with exp2 scale folding + pi
// row permutation; emb->bf16; bins zero.
// ---------------------------------------------------------------------------
__global__ __launch_bounds__(256) void k_prep(
    const float* __restrict__ emb,
    const float* __restrict__ W1, const float* __restrict__ W2,
    const float* __restrict__ Wp1,
    const float* __restrict__ b_ih1, const float* __restrict__ b_hh1,
    const float* __restrict__ b_ih2, const float* __restrict__ b_hh2,
    u16* __restrict__ embb,
    u16* __restrict__ w1b, u16* __restrict__ w2b, u16* __restrict__ wp1b,
    float* __restrict__ bs1, float* __restrict__ bs2,
    float* __restrict__ bins)
{
  const int i = blockIdx.x * 256 + threadIdx.x;   // 65536 threads
  if (i < 512 * 64) {
    const int row = i >> 6, G = row >> 7, rr = row & 127;
    const float s = (G == 2) ? TWOLOG2E : -LOG2E;
    w1b[i] = f2bf(W1[(G * 128 + perm128(rr)) * ISZ + (i & 63)] * s);
  }
  if (i < 512 * 128) {
    const int row = i >> 7, G = row >> 7, rr = row & 127;
    const float s = (G == 2) ? TWOLOG2E : -LOG2E;
    w2b[i] = f2bf(W2[(G * 128 + perm128(rr)) * HSZ + (i & 127)] * s);
  }
  if (i < 64 * 128) wp1b[i] = f2bf(Wp1[i]);
  if (i < 512) {
    const int G = i >> 7, rr = i & 127;
    const float s = (G == 2) ? TWOLOG2E : -LOG2E;
    const int src = G * 128 + perm128(rr);
    bs1[i] = (b_ih1[src] + b_hh1[src]) * s;
    bs2[i] = (b_ih2[src] + b_hh2[src]) * s;
  }
  if (i < NBIN * HSZ) bins[i] = 0.f;
  for (int j = i; j < VSZ * 64; j += 256 * 256) embb[j] = f2bf(emb[j]);
}

// ---------------------------------------------------------------------------
// k_vocab: THE memoization kernel. h0=c0=0 => h1, h2 and the attention-MLP
// energy are pure functions of the TOKEN ID (no recurrence). Compute them
// once per vocab entry (10000) instead of once per position (262144) — 26x
// less work. Datapath = R11-VERIFIED trace_body with NG=2 (LDS-staged
// swizzled weights, pi register-rename); outputs Et[id] and H2t[id][128]
// instead of softmax/ta. 40 blocks x 8 waves x 32 ids = 10240 >= VSZ.
// ---------------------------------------------------------------------------
__global__ __launch_bounds__(512) void k_vocab(
    const u16* __restrict__ embb,
    const u16* __restrict__ w1b, const float* __restrict__ bs1,
    const u16* __restrict__ w2b, const float* __restrict__ bs2,
    const u16* __restrict__ wp1b,
    const float* __restrict__ bp1v, const float* __restrict__ Wp2,
    float* __restrict__ Et, u16* __restrict__ H2t)
{
  __shared__ __align__(16) u16 w1s[384 * 64];    //  48 KB
  __shared__ __align__(16) u16 w2s[384 * 128];   //  96 KB
  const int tid = threadIdx.x;

  // ---- stage w1 (R11 verbatim): compact i@0/g@128/o@256, XOR-swizzled
  for (int i = tid; i < 3072; i += 512) {
    const int r = i >> 3;
    const int src = (r < 128) ? r : r + 128;     // skip f-gate rows
    const int c16 = (i & 7) * 8;
    *(u32x4*)&w1s[r * 64 + (c16 ^ ((r & 7) << 3))] =
        *(const u32x4*)&w1b[src * 64 + c16];
  }
  for (int i = tid; i < 6144; i += 512) {
    const int r = i >> 4;
    const int src = (r < 128) ? r : r + 128;
    const int c16 = (i & 15) * 8;
    *(u32x4*)&w2s[r * 128 + (c16 ^ ((r & 15) << 3))] =
        *(const u32x4*)&w2b[src * 128 + c16];
  }
  __syncthreads();

  const int lane = tid & 63;
  const int col  = lane & 15;
  const int q    = lane >> 4;
  const int sw1  = (col & 7) << 3;
  const int sw2  = col << 3;
  const int wbase = (blockIdx.x * 8 + (tid >> 6)) * 32;   // 32 ids per wave
  const f32x4 z = {0.f, 0.f, 0.f, 0.f};

  // ---- x fragments: vocab id = wbase + g*16 + col (clamped gather)
  short8 xf[2][2];
#pragma unroll
  for (int g = 0; g < 2; ++g) {
    const int id = wbase + g * 16 + col;
    const int idc = (id < VSZ) ? id : 0;
    const u16* xr = embb + (size_t)idc * ISZ + q * 8;
    xf[g][0] = *(const short8*)(xr);
    xf[g][1] = *(const short8*)(xr + 32);
  }

  // ---- LSTM layer 1 (R11 verbatim, NG=2)
  uint32_t pk[2][8][2];
#pragma unroll
  for (int mt = 0; mt < 8; ++mt) {
    f32x4 aI[2], aC[2], aO[2];
#pragma unroll
    for (int g = 0; g < 2; ++g) { aI[g] = z; aC[g] = z; aO[g] = z; }
#pragma unroll
    for (int ks = 0; ks < 2; ++ks) {
      const int off = ((ks * 32 + q * 8) ^ sw1);
      short8 fI = *(const short8*)&w1s[(mt * 16 + col) * ISZ + off];
      short8 fC = *(const short8*)&w1s[(128 + mt * 16 + col) * ISZ + off];
      short8 fO = *(const short8*)&w1s[(256 + mt * 16 + col) * ISZ + off];
#pragma unroll
      for (int g = 0; g < 2; ++g) {
        aI[g] = __builtin_amdgcn_mfma_f32_16x16x32_bf16(fI, xf[g][ks], aI[g], 0, 0, 0);
        aC[g] = __builtin_amdgcn_mfma_f32_16x16x32_bf16(fC, xf[g][ks], aC[g], 0, 0, 0);
        aO[g] = __builtin_amdgcn_mfma_f32_16x16x32_bf16(fO, xf[g][ks], aO[g], 0, 0, 0);
      }
    }
    float bI[4], bC[4], bO[4];
#pragma unroll
    for (int r = 0; r < 4; ++r) {
      const int h = mt * 16 + q * 4 + r;
      bI[r] = bs1[h]; bC[r] = bs1[256 + h]; bO[r] = bs1[384 + h];
    }
#pragma unroll
    for (int g = 0; g < 2; ++g) {
      u16 hv[4];
#pragma unroll
      for (int r = 0; r < 4; ++r) {
        float c = gate2(aI[g][r] + bI[r], aC[g][r] + bC[r]);
        hv[r] = f2bf(gate2(aO[g][r] + bO[r], TWOLOG2E * c));
      }
      pk[g][mt][0] = (uint32_t)hv[0] | ((uint32_t)hv[1] << 16);
      pk[g][mt][1] = (uint32_t)hv[2] | ((uint32_t)hv[3] << 16);
    }
  }

  // ---- h1 fragments: register rename (R6-verified)
  short8 hf[2][4];
#pragma unroll
  for (int g = 0; g < 2; ++g)
#pragma unroll
    for (int ks = 0; ks < 4; ++ks)
      hf[g][ks] = mk8(pk[g][ks][0], pk[g][ks][1], pk[g][ks + 4][0], pk[g][ks + 4][1]);

  // ---- LSTM layer 2 (R11 verbatim, NG=2)
  uint32_t pk2[2][8][2];
#pragma unroll
  for (int mt = 0; mt < 8; ++mt) {
    f32x4 aI[2], aC[2], aO[2];
#pragma unroll
    for (int g = 0; g < 2; ++g) { aI[g] = z; aC[g] = z; aO[g] = z; }
#pragma unroll
    for (int ks = 0; ks < 4; ++ks) {
      const int off = ((ks * 32 + q * 8) ^ sw2);
      short8 fI = *(const short8*)&w2s[(mt * 16 + col) * HSZ + off];
      short8 fC = *(const short8*)&w2s[(128 + mt * 16 + col) * HSZ + off];
      short8 fO = *(const short8*)&w2s[(256 + mt * 16 + col) * HSZ + off];
#pragma unroll
      for (int g = 0; g < 2; ++g) {
        aI[g] = __builtin_amdgcn_mfma_f32_16x16x32_bf16(fI, hf[g][ks], aI[g], 0, 0, 0);
        aC[g] = __builtin_amdgcn_mfma_f32_16x16x32_bf16(fC, hf[g][ks], aC[g], 0, 0, 0);
        aO[g] = __builtin_amdgcn_mfma_f32_16x16x32_bf16(fO, hf[g][ks], aO[g], 0, 0, 0);
      }
    }
    float bI[4], bC[4], bO[4];
#pragma unroll
    for (int r = 0; r < 4; ++r) {
      const int h = mt * 16 + q * 4 + r;
      bI[r] = bs2[h]; bC[r] = bs2[256 + h]; bO[r] = bs2[384 + h];
    }
#pragma unroll
    for (int g = 0; g < 2; ++g) {
      u16 hv[4];
#pragma unroll
      for (int r = 0; r < 4; ++r) {
        float c = gate2(aI[g][r] + bI[r], aC[g][r] + bC[r]);
        hv[r] = f2bf(gate2(aO[g][r] + bO[r], TWOLOG2E * c));
      }
      pk2[g][mt][0] = (uint32_t)hv[0] | ((uint32_t)hv[1] << 16);
      pk2[g][mt][1] = (uint32_t)hv[2] | ((uint32_t)hv[3] << 16);
    }
  }

  // ---- h2 fragments (linear-k) via rename (R6-verified)
  short8 hf2[2][4];
#pragma unroll
  for (int g = 0; g < 2; ++g)
#pragma unroll
    for (int ks = 0; ks < 4; ++ks)
      hf2[g][ks] = mk8(pk2[g][ks][0], pk2[g][ks][1], pk2[g][ks + 4][0], pk2[g][ks + 4][1]);

  // ---- attention-MLP energy (R11 verbatim)
  float ep[2];
#pragma unroll
  for (int g = 0; g < 2; ++g) ep[g] = 0.f;
#pragma unroll
  for (int mt = 0; mt < 4; ++mt) {
    f32x4 acc[2];
#pragma unroll
    for (int g = 0; g < 2; ++g) acc[g] = z;
#pragma unroll
    for (int ks = 0; ks < 4; ++ks) {
      short8 fA = *(const short8*)(wp1b + (size_t)(mt * 16 + col) * HSZ + ks * 32 + q * 8);
#pragma unroll
      for (int g = 0; g < 2; ++g)
        acc[g] = __builtin_amdgcn_mfma_f32_16x16x32_bf16(fA, hf2[g][ks], acc[g], 0, 0, 0);
    }
#pragma unroll
    for (int r = 0; r < 4; ++r) {
      const int hp = mt * 16 + q * 4 + r;
      const float b1 = bp1v[hp];
      const float w2 = Wp2[hp];
#pragma unroll
      for (int g = 0; g < 2; ++g)
        ep[g] += fmaxf(acc[g][r] + b1, 0.f) * w2;
    }
  }
#pragma unroll
  for (int g = 0; g < 2; ++g) {
    ep[g] += __shfl_xor(ep[g], 16);
    ep[g] += __shfl_xor(ep[g], 32);
  }

  // ---- table writes (bp2 omitted: constant shift cancels in softmax)
#pragma unroll
  for (int g = 0; g < 2; ++g) {
    const int id = wbase + g * 16 + col;
    if (id < VSZ) {
      if (q == 0) Et[id] = ep[g];
#pragma unroll
      for (int ks = 0; ks < 4; ++ks)
        *(short8*)&H2t[(size_t)id * HSZ + ks * 32 + q * 8] = hf2[g][ks];
    }
  }
}

// ---------------------------------------------------------------------------
// k_attn: per-trace gather + softmax + weighted sum from the tables.
// 1 wave per trace, 4 waves/block, no LDS. Lane l holds token l; softmax
// over 64 lanes via shfl; weighted sum: lane covers h = lane*2, lane*2+1
// (coalesced 256B H2 row reads, L2-hot: table is 2.6 MB).
// ---------------------------------------------------------------------------
__global__ __launch_bounds__(256) void k_attn(
    const float* __restrict__ Et, const u16* __restrict__ H2t,
    const int* __restrict__ traces, const int* __restrict__ lengths,
    float* __restrict__ bins)
{
  const int wv   = threadIdx.x >> 6;
  const int lane = threadIdx.x & 63;
  const int t    = blockIdx.x * 4 + wv;
  const int len  = lengths[t];
  const int tok  = traces[t * TLEN + lane];
  const bool valid = lane < len;

  float e = valid ? Et[tok] : -3.0e38f;
  float m = e;
#pragma unroll
  for (int off = 1; off < 64; off <<= 1) m = fmaxf(m, __shfl_xor(m, off));
  float w = valid ? __expf(e - m) : 0.f;
  float s = w;
#pragma unroll
  for (int off = 1; off < 64; off <<= 1) s += __shfl_xor(s, off);
  const float wl = w * __builtin_amdgcn_rcpf(s);

  const int hc = lane * 2;
  float a0 = 0.f, a1 = 0.f;
  for (int l = 0; l < len; ++l) {          // len is wave-uniform
    const float wb = __shfl(wl, l);
    const int   tb = __shfl(tok, l);
    const uint32_t hv = *(const uint32_t*)&H2t[(size_t)tb * HSZ + hc];
    a0 += wb * bflo(hv);
    a1 += wb * bfhi(hv);
  }
  float* bin = bins + (size_t)(t & (NBIN - 1)) * HSZ;
  atomicAdd(&bin[hc], a0);
  atomicAdd(&bin[hc + 1], a1);
}

// ---------------------------------------------------------------------------
// k_out (R6-VERIFIED, verbatim): reduce 64 bins -> fin, then 128x128 matvec.
// ---------------------------------------------------------------------------
__global__ __launch_bounds__(128) void k_out(
    const float* __restrict__ bins, const float* __restrict__ W_out,
    const float* __restrict__ b_out, float* __restrict__ out)
{
  const int o = threadIdx.x;      // 0..127
  __shared__ float fs[HSZ];
  float s = 0.f;
#pragma unroll 4
  for (int b = 0; b < NBIN; ++b) s += bins[b * HSZ + o];
  fs[o] = s;
  __syncthreads();
  float acc = b_out[o];
  const float* wr = W_out + (size_t)o * HSZ;
#pragma unroll
  for (int h = 0; h < HSZ; ++h) acc += wr[h] * fs[h];
  out[o] = acc;
}

extern "C" void kernel_launch(void* const* d_in, const int* in_sizes, int n_in,
                              void* d_out, int out_size, void* d_ws, size_t ws_size,
                              hipStream_t stream)
{
  const float* emb   = (const float*)d_in[0];
  const float* W_ih1 = (const float*)d_in[1];
  // d_in[2] = W_hh1: unused (h0 = 0)
  const float* b_ih1 = (const float*)d_in[3];
  const float* b_hh1 = (const float*)d_in[4];
  const float* W_ih2 = (const float*)d_in[5];
  // d_in[6] = W_hh2: unused
  const float* b_ih2 = (const float*)d_in[7];
  const float* b_hh2 = (const float*)d_in[8];
  const float* Wp1   = (const float*)d_in[9];
  const float* bp1   = (const float*)d_in[10];
  const float* Wp2   = (const float*)d_in[11];
  const float* bp2   = (const float*)d_in[12];  // cancels in softmax: unused
  const float* W_out = (const float*)d_in[13];
  const float* b_out = (const float*)d_in[14];
  const int* traces  = (const int*)d_in[15];
  const int* lengths = (const int*)d_in[16];
  (void)bp2;

  char* ws = (char*)d_ws;
  u16*   w1b  = (u16*)(ws);                  // 512*64*2    = 65536 B
  u16*   w2b  = (u16*)(ws + 65536);          // 512*128*2   = 131072 B
  u16*   wp1b = (u16*)(ws + 196608);         // 64*128*2    = 16384 B
  float* bs1  = (float*)(ws + 212992);       // 2048 B
  float* bs2  = (float*)(ws + 215040);       // 2048 B
  float* bins = (float*)(ws + 217088);       // 64*128*4    = 32768 B
  u16*   embb = (u16*)(ws + 249856);         // 10000*64*2  = 1280000 B
  float* Et   = (float*)(ws + 1529856);      // 10240*4     = 40960 B
  u16*   H2t  = (u16*)(ws + 1570816);        // 10240*128*2 = 2621440 B

  k_prep<<<256, 256, 0, stream>>>(emb, W_ih1, W_ih2, Wp1, b_ih1, b_hh1,
                                  b_ih2, b_hh2, embb, w1b, w2b, wp1b,
                                  bs1, bs2, bins);
  k_vocab<<<40, 512, 0, stream>>>(embb, w1b, bs1, w2b, bs2, wp1b,
                                  bp1, Wp2, Et, H2t);
  k_attn<<<NTRACE / 4, 256, 0, stream>>>(Et, H2t, traces, lengths, bins);
  k_out<<<1, 128, 0, stream>>>(bins, W_out, b_out, (float*)d_out);
}